// Round 14
// baseline (41.749 us; speedup 1.0000x reference)
//
#include <hip/hip_runtime.h>
#include <string.h>

// Fused ConvNet, single dispatch: conv7x7 s3 (3->4) -> ^2 -> FC 324->64 -> ^2 -> FC 64->10
// conv + fc1 on v_mfma_f32_16x16x32_f16; x staged as fp16 windows in LDS
// (one aligned ds_read_b128 per A-fragment).
// Round 14: NS=32 + double-buffered WIN (ONE barrier/step) + full-row staging
// (96 threads x 8 float4, prefetch depth 2) + balanced tiles (stagers in waves
// 0-1 carry 1 tile; waves 2-3 carry 2). LDS 50688 B; grid 512 -> 2 blocks/CU.

typedef _Float16 f16;
typedef f16 f16x8 __attribute__((ext_vector_type(8)));
typedef __fp16 fp16x2 __attribute__((ext_vector_type(2)));
typedef float f32x4 __attribute__((ext_vector_type(4)));

#define NS     32                      // samples per block
#define WIN_B  13824                   // one WIN buffer: [3][32][9][8] halves
#define YS_B   27648                   // = 2*WIN_B
#define LDS_B  (27648 + NS * 720)      // + YS[NS][360]h = 50688

__device__ __forceinline__ unsigned pack_rtz(float a, float b) {
    fp16x2 h = __builtin_amdgcn_cvt_pkrtz(a, b);
    unsigned u; memcpy(&u, &h, 4); return u;
}

// write 9 windows (8 halves each) of one row from 16 packed dwords
__device__ __forceinline__ void write_windows(f16* wptr, const unsigned h[16]) {
#pragma unroll
    for (int ow = 0; ow < 9; ow += 2) {          // 3*ow even: direct
        int d = (3 * ow) >> 1;
        uint4 v; v.x = h[d]; v.y = h[d+1]; v.z = h[d+2]; v.w = h[d+3];
        *reinterpret_cast<uint4*>(wptr + ow * 8) = v;
    }
#pragma unroll
    for (int ow = 1; ow < 9; ow += 2) {          // 3*ow odd: shift one half
        int d = (3 * ow) >> 1;
        uint4 v;
        v.x = __builtin_amdgcn_alignbit(h[d+1], h[d],   16);
        v.y = __builtin_amdgcn_alignbit(h[d+2], h[d+1], 16);
        v.z = __builtin_amdgcn_alignbit(h[d+3], h[d+2], 16);
        v.w = __builtin_amdgcn_alignbit(h[d+4], h[d+3], 16);
        *reinterpret_cast<uint4*>(wptr + ow * 8) = v;
    }
}

__global__ __launch_bounds__(256, 2) void convnet_mfma(
    const float* __restrict__ x,
    const float* __restrict__ cw,      // [4][3][7][7]
    const float* __restrict__ fc1w,    // [64][324]
    const float* __restrict__ fc1b,
    const float* __restrict__ fc2w,    // [10][64]
    const float* __restrict__ fc2b,
    float* __restrict__ out)
{
    __shared__ unsigned char lds[LDS_B];
    f16* YS   = (f16*)(lds + YS_B);                // [NS][360] halves
    float* HSQ = (float*)lds;                      // overlay on WIN (post-conv), [NS][65]

    const int t    = threadIdx.x;
    const int lane = t & 63;
    const int w    = t >> 6;
    const int g    = lane >> 4;
    const int lr   = lane & 15;
    const size_t base_s = (size_t)blockIdx.x * NS;

    // ---- conv W fragments (in-kernel fp16 cvt): lane holds col=lr, k=st*32+g*8..+7
    f16x8 wcf[6];
#pragma unroll
    for (int st = 0; st < 6; ++st) {
        f16x8 v = {0, 0, 0, 0, 0, 0, 0, 0};
        int seg = st * 4 + g;
        if (lr < 4 && seg <= 20) {
            int ci = seg >= 14 ? 2 : (seg >= 7 ? 1 : 0);
            int kh = seg - ci * 7;
            const float* wr = cw + ((lr * 3 + ci) * 7 + kh) * 7;
#pragma unroll
            for (int j = 0; j < 7; ++j) v[j] = (f16)wr[j];
        }
        wcf[st] = v;
    }

    // seg byte offsets (seg = st*4+g, clamped; pad segs have zero weights)
    int seg2off[6];
#pragma unroll
    for (int st = 0; st < 6; ++st) {
        int seg  = st * 4 + g;
        int segc = seg > 20 ? 20 : seg;
        int ci   = segc >= 14 ? 2 : (segc >= 7 ? 1 : 0);
        int kh   = segc - ci * 7;
        seg2off[st] = ci * 4608 + kh * 144;        // bytes: ci*(32*9*16) + kh*(9*16)
    }

    // conv tiles (6 tiles of 16 rows over 81 positions):
    // stager waves (0,1) get 1 tile: w0:{2} w1:{5}; waves 2,3 get 2: w2:{0,3} w3:{1,4}
    const int ntiles = (w >= 2) ? 2 : 1;
    const int tileA  = (w == 0) ? 2 : (w == 1) ? 5 : (w == 2) ? 0 : 1;
    const int tileB  = (w == 2) ? 3 : 4;           // used only if ntiles==2
    int rowbase[2], pbase[2];
#pragma unroll
    for (int ti = 0; ti < 2; ++ti) {
        int tc   = ti ? tileB : tileA;
        int grow = tc * 16 + lr;
        int p    = grow > 80 ? 80 : grow;
        int oh   = (p * 57) >> 9;
        int ow   = p - oh * 9;
        rowbase[ti] = oh * 432 + ow * 16;          // bytes within a WIN buffer
        pbase[ti]   = tc * 16 + g * 4;             // C rows p = pbase + r
    }

    // staging identity: 96 threads own one (ci,row); 8 float4 = full 32-col row
    const bool stg  = t < 96;
    const int  sci  = t >> 5;
    const int  srow = t & 31;
    const int  goff = sci * 1024 + srow * 32;
    const int  woff = sci * 2304 + srow * 72;      // halves within a WIN buffer

    // ---- prologue ----
    float4 ldv[8];
    unsigned hh[16];
    if (stg) {                                     // sample 0
        const float* gp = x + base_s * 3072 + goff;
#pragma unroll
        for (int i = 0; i < 8; ++i) ldv[i] = *(const float4*)(gp + 4 * i);
    }
    // zero YS tails: halves [324,360) per sample = 18 dwords x NS samples = 576
#pragma unroll
    for (int i = 0; i < 3; ++i) {
        int idx = i * 256 + t;
        if (idx < NS * 18) {
            int si = idx / 18, d = idx - si * 18;
            *(unsigned*)(YS + si * 360 + 324 + d * 2) = 0u;
        }
    }
    if (stg) {
#pragma unroll
        for (int i = 0; i < 8; ++i) {
            hh[2*i]   = pack_rtz(ldv[i].x, ldv[i].y);
            hh[2*i+1] = pack_rtz(ldv[i].z, ldv[i].w);
        }
        write_windows((f16*)(lds) + woff, hh);     // buf 0
        const float* gp = x + (base_s + 1) * 3072 + goff;   // sample 1
#pragma unroll
        for (int i = 0; i < 8; ++i) ldv[i] = *(const float4*)(gp + 4 * i);
    }
    __syncthreads();

    // ---- NS steps, ONE barrier each (double-buffered WIN) ----
    for (int s = 0; s < NS; ++s) {
        const unsigned char* winb = lds + (s & 1) * WIN_B;          // read buf
        f16* wino = (f16*)(lds + ((s & 1) ^ 1) * WIN_B);            // write buf
        f16* ysp  = YS + s * 360;

        __builtin_amdgcn_s_setprio(1);
#pragma unroll
        for (int ti = 0; ti < 2; ++ti) {
            if (ti < ntiles) {
                const unsigned char* pA = winb + rowbase[ti];
                f32x4 acc = {0.f, 0.f, 0.f, 0.f};
#pragma unroll
                for (int st = 0; st < 6; ++st) {
                    f16x8 af = *(const f16x8*)(pA + seg2off[st]);
                    acc = __builtin_amdgcn_mfma_f32_16x16x32_f16(af, wcf[st], acc, 0, 0, 0);
                }
                if (lr < 4) {
#pragma unroll
                    for (int r = 0; r < 4; ++r) {
                        int p = pbase[ti] + r;
                        if (p < 81) {
                            float y = acc[r];
                            ysp[lr * 81 + p] = (f16)(y * y);
                        }
                    }
                }
            }
        }
        __builtin_amdgcn_s_setprio(0);

        if (s < NS - 1 && stg) {                   // stage sample s+1 into wino
#pragma unroll
            for (int i = 0; i < 8; ++i) {
                hh[2*i]   = pack_rtz(ldv[i].x, ldv[i].y);
                hh[2*i+1] = pack_rtz(ldv[i].z, ldv[i].w);
            }
            write_windows(wino + woff, hh);
        }
        if (s < NS - 2 && stg) {                   // prefetch sample s+2
            const float* gp = x + (base_s + s + 2) * 3072 + goff;
#pragma unroll
            for (int i = 0; i < 8; ++i) ldv[i] = *(const float4*)(gp + 4 * i);
        }
        __syncthreads();
    }

    // ---- fc1: M=32 (two 16-row tiles share one weight load/split), N=64, K=352 ----
    {
        f32x4 a0 = {0.f, 0.f, 0.f, 0.f};
        f32x4 a1 = {0.f, 0.f, 0.f, 0.f};
        const int n = w * 16 + lr;
        const float* w1r = fc1w + n * 324;
        __builtin_amdgcn_s_setprio(1);
#pragma unroll
        for (int st = 0; st < 10; ++st) {
            f16x8 av0 = *(const f16x8*)(YS +        lr  * 360 + st * 32 + g * 8);
            f16x8 av1 = *(const f16x8*)(YS + (16 + lr) * 360 + st * 32 + g * 8);
            float4 v0 = *(const float4*)(w1r + st * 32 + g * 8);
            float4 v1 = *(const float4*)(w1r + st * 32 + g * 8 + 4);
            float vv[8] = {v0.x, v0.y, v0.z, v0.w, v1.x, v1.y, v1.z, v1.w};
            f16x8 bh, bl;
#pragma unroll
            for (int j = 0; j < 8; ++j) {
                f16 hi = (f16)vv[j];
                bh[j] = hi;
                bl[j] = (f16)(vv[j] - (float)hi);
            }
            a0 = __builtin_amdgcn_mfma_f32_16x16x32_f16(av0, bh, a0, 0, 0, 0);
            a0 = __builtin_amdgcn_mfma_f32_16x16x32_f16(av0, bl, a0, 0, 0, 0);
            a1 = __builtin_amdgcn_mfma_f32_16x16x32_f16(av1, bh, a1, 0, 0, 0);
            a1 = __builtin_amdgcn_mfma_f32_16x16x32_f16(av1, bl, a1, 0, 0, 0);
        }
        {   // st = 10: k = 320..351, only 320..323 carry data (g==0, j<4)
            f16x8 av0 = *(const f16x8*)(YS +        lr  * 360 + 320 + g * 8);
            f16x8 av1 = *(const f16x8*)(YS + (16 + lr) * 360 + 320 + g * 8);
            f16x8 bh = {0,0,0,0,0,0,0,0}, bl = {0,0,0,0,0,0,0,0};
            if (g == 0) {
                float4 v0 = *(const float4*)(w1r + 320);
                float vv[4] = {v0.x, v0.y, v0.z, v0.w};
#pragma unroll
                for (int j = 0; j < 4; ++j) {
                    f16 hi = (f16)vv[j];
                    bh[j] = hi;
                    bl[j] = (f16)(vv[j] - (float)hi);
                }
            }
            a0 = __builtin_amdgcn_mfma_f32_16x16x32_f16(av0, bh, a0, 0, 0, 0);
            a0 = __builtin_amdgcn_mfma_f32_16x16x32_f16(av0, bl, a0, 0, 0, 0);
            a1 = __builtin_amdgcn_mfma_f32_16x16x32_f16(av1, bh, a1, 0, 0, 0);
            a1 = __builtin_amdgcn_mfma_f32_16x16x32_f16(av1, bl, a1, 0, 0, 0);
        }
        __builtin_amdgcn_s_setprio(0);
        float bias = fc1b[n];
#pragma unroll
        for (int r = 0; r < 4; ++r) {
            int s0 = g * 4 + r;                // samples 0..15
            float h0 = a0[r] + bias;
            HSQ[s0 * 65 + n] = h0 * h0;
            float h1 = a1[r] + bias;           // samples 16..31
            HSQ[(s0 + 16) * 65 + n] = h1 * h1;
        }
    }
    __syncthreads();

    // ---------------- fc2: NS*10 = 320 outputs ----------------
#pragma unroll
    for (int b = 0; b < 2; ++b) {
        int idx = b * 256 + t;
        if (idx < NS * 10) {
            int sj = idx / 10, j = idx - sj * 10;
            float a = fc2b[j];
            const float* wr = fc2w + j * 64;
            const float* hv = &HSQ[sj * 65];
#pragma unroll
            for (int i = 0; i < 64; ++i) a += wr[i] * hv[i];
            out[(base_s + sj) * 10 + j] = a;
        }
    }
}

extern "C" void kernel_launch(void* const* d_in, const int* in_sizes, int n_in,
                              void* d_out, int out_size, void* d_ws, size_t ws_size,
                              hipStream_t stream) {
    const float* x    = (const float*)d_in[0];
    const float* cw   = (const float*)d_in[1];
    const float* fc1w = (const float*)d_in[2];
    const float* fc1b = (const float*)d_in[3];
    const float* fc2w = (const float*)d_in[4];
    const float* fc2b = (const float*)d_in[5];
    float* out = (float*)d_out;

    const int B = in_sizes[0] / 3072;      // 16384
    hipLaunchKernelGGL(convnet_mfma, dim3(B / NS), dim3(256), 0, stream,
                       x, cw, fc1w, fc1b, fc2w, fc2b, out);
}